// Round 5
// baseline (102.766 us; speedup 1.0000x reference)
//
#include <hip/hip_runtime.h>
#include <hip/hip_bf16.h>

// CorrelationLayerCosineSimilarity via banded bf16 MFMA GEMM.
// Per (b,h): Out[w,d] = sum_c x1[c,w]*x2p[c,w+d] / max(n1[w]*n2[w+d], 1e-6)
// B=4,C=256,H=128,W=256,D=41.
//
// Round 5: round-3 structure (512 thr / 8 waves / 2 w-tiles per wave; 62 us)
// + 2-deep register prefetch. Two load sets ping-pong (K-loop unrolled x2,
// all indices static): loads for ks+2 issue right after pack(ks) frees the
// set, so pack(ks+1) only needs a partial vmcnt — the memory pipe stays fed
// across pack/barrier/MFMA instead of draining every K-step (round 4 showed
// occupancy is NOT the lever; the serialized load->drain chain is).
//
// LDS (47040B): A[w 0..255][kc 0..31] bf16, 80B rows (4x16B slots + pad slot,
// logical slot s of row w at physical (s+w)%5 -> conflict-free b128 reads).
// B[w' 0..303] same (rows 256..303 zeroed once). Norms at NBASE.
// Epilogue: per-wave 16x66 f32 transpose -> normalize -> [d][w] float4 stores.

#define B_   4
#define C_   256
#define H_   128
#define W_   256
#define ND_  41
#define HW_  (H_ * W_)
#define CHW_ (C_ * HW_)
#define EPS_ 1e-6f

typedef __attribute__((ext_vector_type(4))) float f32x4;
typedef __attribute__((ext_vector_type(8))) short bf16x8;

#define ABASE 0
#define BBASE 20480            // A: 256*80
#define NBASE 44800            // B ends: BBASE + 304*80
#define LDSZ  47040            // + 560 f32 norm area

__device__ __forceinline__ unsigned bfr(float x) {   // fp32 -> bf16 bits, RNE
  unsigned u = __builtin_bit_cast(unsigned, x);
  return (u + 0x7fffu + ((u >> 16) & 1u)) >> 16;
}

__global__ __launch_bounds__(512, 4)
void corr_mfma(const float* __restrict__ x1, const float* __restrict__ x2,
               float* __restrict__ out) {
  __shared__ __align__(16) char lds[LDSZ];

  const int tid = threadIdx.x;
  const int l   = tid & 63;
  const int v   = tid >> 6;          // wave id = staging c-quad id
  const int m   = l & 15;
  const int g   = l >> 4;

  const int r = blockIdx.x;
  const int b = r >> 7;
  const int h = r & (H_ - 1);

  const float* X1 = x1 + b * CHW_ + h * W_;
  const float* X2 = x2 + b * CHW_ + h * W_;

  // ---- prologue zero-init: norm accumulators + B pad rows 256..303 ----
  if (tid < 560) ((float*)(lds + NBASE))[tid] = 0.f;
  {
    unsigned* zp = (unsigned*)(lds + BBASE + 256 * 80);   // 48 rows * 80B
    zp[tid] = 0u;
    if (tid < 960 - 512) zp[tid + 512] = 0u;
  }

  // ---- loop-invariant addresses ----
  int wadr1[4];                       // staging write addrs (x1; x2 = +BBASE)
#pragma unroll
  for (int j = 0; j < 4; ++j) {
    int w = 4 * l + j;
    wadr1[j] = ABASE + w * 80 + (((v >> 1) + w) % 5) * 16 + (v & 1) * 8;
  }
  int adrA[2], adrB[2][4];            // frag read addrs
#pragma unroll
  for (int i = 0; i < 2; ++i) {
    int wt = v + 8 * i;
    int rowA = 16 * wt + m;
    adrA[i] = ABASE + rowA * 80 + ((g + rowA) % 5) * 16;
#pragma unroll
    for (int c = 0; c < 4; ++c) {
      int col = 16 * (wt + c) + m;    // <= 303
      adrB[i][c] = BBASE + col * 80 + ((g + col) % 5) * 16;
    }
  }

  f32x4 acc[2][4];
#pragma unroll
  for (int i = 0; i < 2; ++i)
#pragma unroll
    for (int c = 0; c < 4; ++c) acc[i][c] = (f32x4){0.f, 0.f, 0.f, 0.f};
  float ssq1[4] = {0.f, 0.f, 0.f, 0.f}, ssq2[4] = {0.f, 0.f, 0.f, 0.f};

  // ---- dual register sets: wave v loads channels ks*32 + 4v..4v+3 ----
  f32x4 r1A[4], r2A[4], r1B[4], r2B[4];

  auto loadset = [&](f32x4 (&r1)[4], f32x4 (&r2)[4], int ks) {
    const float* p1 = X1 + (ks * 32 + 4 * v) * HW_ + 4 * l;
    const float* p2 = X2 + (ks * 32 + 4 * v) * HW_ + 4 * l;
#pragma unroll
    for (int i = 0; i < 4; ++i) {
      r1[i] = *(const f32x4*)(p1 + i * HW_);
      r2[i] = *(const f32x4*)(p2 + i * HW_);
    }
  };

  // body: pack set S (data of step ks), refill S with ks+2, then MFMA(ks)
  auto body = [&](f32x4 (&r1)[4], f32x4 (&r2)[4], int ks) {
    __syncthreads();                  // prior frag reads done; safe to write
#pragma unroll
    for (int j = 0; j < 4; ++j) {
#pragma unroll
      for (int i = 0; i < 4; ++i) {
        ssq1[j] += r1[i][j] * r1[i][j];
        ssq2[j] += r2[i][j] * r2[i][j];
      }
      uint2 p1, p2;
      p1.x = bfr(r1[0][j]) | (bfr(r1[1][j]) << 16);
      p1.y = bfr(r1[2][j]) | (bfr(r1[3][j]) << 16);
      p2.x = bfr(r2[0][j]) | (bfr(r2[1][j]) << 16);
      p2.y = bfr(r2[2][j]) | (bfr(r2[3][j]) << 16);
      *(uint2*)(lds + wadr1[j]) = p1;
      *(uint2*)(lds + wadr1[j] + (BBASE - ABASE)) = p2;
    }
    if (ks < 6) loadset(r1, r2, ks + 2);   // refill freed set; 2 iters ahead
    __syncthreads();                  // tile ready
    // ---- compute: 10 ds_read_b128 + 8 MFMA ----
    bf16x8 a0 = *(const bf16x8*)(lds + adrA[0]);
    bf16x8 a1 = *(const bf16x8*)(lds + adrA[1]);
#pragma unroll
    for (int c = 0; c < 4; ++c) {
      bf16x8 b0 = *(const bf16x8*)(lds + adrB[0][c]);
      acc[0][c] = __builtin_amdgcn_mfma_f32_16x16x32_bf16(a0, b0, acc[0][c], 0, 0, 0);
    }
#pragma unroll
    for (int c = 0; c < 4; ++c) {
      bf16x8 b1 = *(const bf16x8*)(lds + adrB[1][c]);
      acc[1][c] = __builtin_amdgcn_mfma_f32_16x16x32_bf16(a1, b1, acc[1][c], 0, 0, 0);
    }
  };

  loadset(r1A, r2A, 0);
  loadset(r1B, r2B, 1);

#pragma unroll
  for (int ks = 0; ks < 8; ks += 2) {
    body(r1A, r2A, ks);
    body(r1B, r2B, ks + 1);
  }

  // ---- norms: LDS atomic reduce of fp32 ssq, then sqrt in place ----
  float* nsq = (float*)(lds + NBASE);
#pragma unroll
  for (int j = 0; j < 4; ++j) {
    atomicAdd(nsq + 4 * l + j, ssq1[j]);            // n1sq[w]
    atomicAdd(nsq + 256 + 4 * l + j, ssq2[j]);      // n2sq[w'], w' < 256
  }
  __syncthreads();                    // also: all frag reads of A/B done
  if (tid < 512) nsq[tid] = sqrtf(nsq[tid]);
  if (tid < 48)  nsq[512 + tid] = sqrtf(nsq[512 + tid]);   // pad cols = 0
  __syncthreads();

  // ---- epilogue: per-wave transpose -> normalize -> coalesced stores ----
  float* Sw  = (float*)(lds + v * 4224);            // 16 x 66 f32, overlays A
  float* n1s = nsq;                                 // [256]
  float* n2s = nsq + 256;                           // [304]
  const int wq = l & 3, dd = l >> 2;
#pragma unroll
  for (int i = 0; i < 2; ++i) {
    int wt = v + 8 * i;
#pragma unroll
    for (int c = 0; c < 4; ++c)
#pragma unroll
      for (int rr = 0; rr < 4; ++rr)
        Sw[(4 * g + rr) * 66 + 16 * c + m] = acc[i][c][rr];
    // wave-internal LDS RAW: compiler inserts lgkmcnt wait
#pragma unroll
    for (int p = 0; p < 3; ++p) {
      int d  = 16 * p + dd;
      int w0 = 16 * wt + 4 * wq;
      f32x4 o;
#pragma unroll
      for (int j = 0; j < 4; ++j) {
        int mm = 4 * wq + j;                        // w-local
        float dot = Sw[mm * 66 + mm + d];           // col = w-local + d
        o[j] = dot / fmaxf(n1s[w0 + j] * n2s[w0 + j + d], EPS_);
      }
      if (d <= 40)
        *(f32x4*)(out + ((b * ND_ + d) * H_ + h) * W_ + w0) = o;
    }
  }
}

extern "C" void kernel_launch(void* const* d_in, const int* in_sizes, int n_in,
                              void* d_out, int out_size, void* d_ws, size_t ws_size,
                              hipStream_t stream) {
  const float* x1 = (const float*)d_in[0];
  const float* x2 = (const float*)d_in[1];
  float* out = (float*)d_out;
  dim3 grid(B_ * H_);
  dim3 block(512);
  hipLaunchKernelGGL(corr_mfma, grid, block, 0, stream, x1, x2, out);
}

// Round 6
// 58.186 us; speedup vs baseline: 1.7662x; 1.7662x over previous
//
#include <hip/hip_runtime.h>
#include <hip/hip_bf16.h>

// CorrelationLayerCosineSimilarity via banded bf16 MFMA GEMM.
// Per (b,h): Out[w,d] = sum_c x1[c,w]*x2p[c,w+d] / max(n1[w]*n2[w+d], 1e-6)
// B=4,C=256,H=128,W=256,D=41.
//
// Round 6: round-3 structure (512 thr / 8 waves / 2 w-tiles per wave) with
// RAW-BARRIER phase boundaries (m201 template): sched_barrier(0) +
// "s_waitcnt lgkmcnt(0)" (asm, memory clobber) + s_barrier + sched_barrier(0).
//  - raw s_barrier has NO implied vmcnt drain -> global prefetch loads stay
//    in flight across both barriers (HIP __syncthreads drains vmcnt(0)).
//  - the asm memory clobbers pin the loads inside their phase: the compiler
//    can no longer sink them to the use site (rounds 3-5 had VGPR=56..64,
//    proving the "prefetch" was silently sunk -> zero latency cover).
//  - 1-deep: loads for ks+1 issue right after pack(ks) frees the registers,
//    consumed at pack(ks+1) -> a full iteration of cover.
// Cross-wave LDS safety: every wave drains its own lgkmcnt before ARRIVING
// at each barrier (reads done before B1, writes done before B2). Control
// flow is wave-uniform -> barrier counts match.
//
// LDS (47040B): A[w 0..255][kc 0..31] bf16, 80B rows (4x16B slots + pad slot,
// logical slot s of row w at physical (s+w)%5 -> conflict-free b128 reads).
// B[w' 0..303] same (rows 256..303 zeroed once). Norms at NBASE.
// Epilogue: per-wave 16x66 f32 transpose -> normalize -> [d][w] float4 stores.

#define B_   4
#define C_   256
#define H_   128
#define W_   256
#define ND_  41
#define HW_  (H_ * W_)
#define CHW_ (C_ * HW_)
#define EPS_ 1e-6f

typedef __attribute__((ext_vector_type(4))) float f32x4;
typedef __attribute__((ext_vector_type(8))) short bf16x8;

#define ABASE 0
#define BBASE 20480            // A: 256*80
#define NBASE 44800            // B ends: BBASE + 304*80
#define LDSZ  47040            // + 560 f32 norm area

// Phase boundary: own-lgkm drain + raw barrier, loads stay in flight.
#define PHASE_BAR() do {                                         \
    __builtin_amdgcn_sched_barrier(0);                           \
    asm volatile("s_waitcnt lgkmcnt(0)" ::: "memory");           \
    __builtin_amdgcn_s_barrier();                                \
    __builtin_amdgcn_sched_barrier(0);                           \
  } while (0)

__device__ __forceinline__ unsigned bfr(float x) {   // fp32 -> bf16 bits, RNE
  unsigned u = __builtin_bit_cast(unsigned, x);
  return (u + 0x7fffu + ((u >> 16) & 1u)) >> 16;
}

__global__ __launch_bounds__(512, 4)
void corr_mfma(const float* __restrict__ x1, const float* __restrict__ x2,
               float* __restrict__ out) {
  __shared__ __align__(16) char lds[LDSZ];

  const int tid = threadIdx.x;
  const int l   = tid & 63;
  const int v   = tid >> 6;          // wave id = staging c-quad id
  const int m   = l & 15;
  const int g   = l >> 4;

  const int r = blockIdx.x;
  const int b = r >> 7;
  const int h = r & (H_ - 1);

  const float* X1 = x1 + b * CHW_ + h * W_;
  const float* X2 = x2 + b * CHW_ + h * W_;

  // ---- prologue zero-init: norm accumulators + B pad rows 256..303 ----
  if (tid < 560) ((float*)(lds + NBASE))[tid] = 0.f;
  {
    unsigned* zp = (unsigned*)(lds + BBASE + 256 * 80);   // 48 rows * 80B
    zp[tid] = 0u;
    if (tid < 960 - 512) zp[tid + 512] = 0u;
  }

  // ---- loop-invariant addresses ----
  int wadr1[4];                       // staging write addrs (x1; x2 = +BBASE)
#pragma unroll
  for (int j = 0; j < 4; ++j) {
    int w = 4 * l + j;
    wadr1[j] = ABASE + w * 80 + (((v >> 1) + w) % 5) * 16 + (v & 1) * 8;
  }
  int adrA[2], adrB[2][4];            // frag read addrs
#pragma unroll
  for (int i = 0; i < 2; ++i) {
    int wt = v + 8 * i;
    int rowA = 16 * wt + m;
    adrA[i] = ABASE + rowA * 80 + ((g + rowA) % 5) * 16;
#pragma unroll
    for (int c = 0; c < 4; ++c) {
      int col = 16 * (wt + c) + m;    // <= 303
      adrB[i][c] = BBASE + col * 80 + ((g + col) % 5) * 16;
    }
  }

  f32x4 acc[2][4];
#pragma unroll
  for (int i = 0; i < 2; ++i)
#pragma unroll
    for (int c = 0; c < 4; ++c) acc[i][c] = (f32x4){0.f, 0.f, 0.f, 0.f};
  float ssq1[4] = {0.f, 0.f, 0.f, 0.f}, ssq2[4] = {0.f, 0.f, 0.f, 0.f};

  // ---- single register set; wave v stages channels ks*32 + 4v..4v+3 ----
  f32x4 r1[4], r2[4];
  auto loadset = [&](int ks) {
    const float* p1 = X1 + (ks * 32 + 4 * v) * HW_ + 4 * l;
    const float* p2 = X2 + (ks * 32 + 4 * v) * HW_ + 4 * l;
#pragma unroll
    for (int i = 0; i < 4; ++i) {
      r1[i] = *(const f32x4*)(p1 + i * HW_);
      r2[i] = *(const f32x4*)(p2 + i * HW_);
    }
  };

  loadset(0);

  for (int ks = 0; ks < 8; ++ks) {
    PHASE_BAR();                      // B1: all waves done reading prev tile
    // ---- pack phase: ssq + bf16 pack + transposed LDS write ----
#pragma unroll
    for (int j = 0; j < 4; ++j) {
#pragma unroll
      for (int i = 0; i < 4; ++i) {
        ssq1[j] += r1[i][j] * r1[i][j];
        ssq2[j] += r2[i][j] * r2[i][j];
      }
      uint2 p1, p2;
      p1.x = bfr(r1[0][j]) | (bfr(r1[1][j]) << 16);
      p1.y = bfr(r1[2][j]) | (bfr(r1[3][j]) << 16);
      p2.x = bfr(r2[0][j]) | (bfr(r2[1][j]) << 16);
      p2.y = bfr(r2[2][j]) | (bfr(r2[3][j]) << 16);
      *(uint2*)(lds + wadr1[j]) = p1;
      *(uint2*)(lds + wadr1[j] + (BBASE - ABASE)) = p2;
    }
    if (ks < 7) loadset(ks + 1);      // refill freed regs; stays in flight
                                      // across B2/B1 (raw barriers, no drain)
    PHASE_BAR();                      // B2: tile ready
    // ---- compute phase: 10 ds_read_b128 + 8 MFMA ----
    bf16x8 a0 = *(const bf16x8*)(lds + adrA[0]);
    bf16x8 a1 = *(const bf16x8*)(lds + adrA[1]);
#pragma unroll
    for (int c = 0; c < 4; ++c) {
      bf16x8 b0 = *(const bf16x8*)(lds + adrB[0][c]);
      acc[0][c] = __builtin_amdgcn_mfma_f32_16x16x32_bf16(a0, b0, acc[0][c], 0, 0, 0);
    }
#pragma unroll
    for (int c = 0; c < 4; ++c) {
      bf16x8 b1 = *(const bf16x8*)(lds + adrB[1][c]);
      acc[1][c] = __builtin_amdgcn_mfma_f32_16x16x32_bf16(a1, b1, acc[1][c], 0, 0, 0);
    }
  }

  // ---- norms: LDS atomic reduce of fp32 ssq, then sqrt in place ----
  float* nsq = (float*)(lds + NBASE);
#pragma unroll
  for (int j = 0; j < 4; ++j) {
    atomicAdd(nsq + 4 * l + j, ssq1[j]);            // n1sq[w]
    atomicAdd(nsq + 256 + 4 * l + j, ssq2[j]);      // n2sq[w'], w' < 256
  }
  __syncthreads();                    // all frag reads of A/B also done
  if (tid < 512) nsq[tid] = sqrtf(nsq[tid]);
  if (tid < 48)  nsq[512 + tid] = sqrtf(nsq[512 + tid]);   // pad cols = 0
  __syncthreads();

  // ---- epilogue: per-wave transpose -> normalize -> coalesced stores ----
  float* Sw  = (float*)(lds + v * 4224);            // 16 x 66 f32, overlays A
  float* n1s = nsq;                                 // [256]
  float* n2s = nsq + 256;                           // [304]
  const int wq = l & 3, dd = l >> 2;
#pragma unroll
  for (int i = 0; i < 2; ++i) {
    int wt = v + 8 * i;
#pragma unroll
    for (int c = 0; c < 4; ++c)
#pragma unroll
      for (int rr = 0; rr < 4; ++rr)
        Sw[(4 * g + rr) * 66 + 16 * c + m] = acc[i][c][rr];
    // wave-internal LDS RAW: compiler inserts lgkmcnt wait
#pragma unroll
    for (int p = 0; p < 3; ++p) {
      int d  = 16 * p + dd;
      int w0 = 16 * wt + 4 * wq;
      f32x4 o;
#pragma unroll
      for (int j = 0; j < 4; ++j) {
        int mm = 4 * wq + j;                        // w-local
        float dot = Sw[mm * 66 + mm + d];           // col = w-local + d
        o[j] = dot / fmaxf(n1s[w0 + j] * n2s[w0 + j + d], EPS_);
      }
      if (d <= 40)
        *(f32x4*)(out + ((b * ND_ + d) * H_ + h) * W_ + w0) = o;
    }
  }
}

extern "C" void kernel_launch(void* const* d_in, const int* in_sizes, int n_in,
                              void* d_out, int out_size, void* d_ws, size_t ws_size,
                              hipStream_t stream) {
  const float* x1 = (const float*)d_in[0];
  const float* x2 = (const float*)d_in[1];
  float* out = (float*)d_out;
  dim3 grid(B_ * H_);
  dim3 block(512);
  hipLaunchKernelGGL(corr_mfma, grid, block, 0, stream, x1, x2, out);
}